// Round 1
// baseline (583.787 us; speedup 1.0000x reference)
//
#include <hip/hip_runtime.h>
#include <hip/hip_bf16.h>
#include <cstdint>

#define NUM_TOKENS 8192
#define IN_DIM 4096
#define OUT_DIM 4096
#define NUM_AD 8
#define RANK 64
#define RTOT (NUM_AD * RANK)           // 512
#define KAUG (IN_DIM + RTOT)           // 4608

typedef __bf16 bf16x8 __attribute__((ext_vector_type(8)));
typedef float f32x4 __attribute__((ext_vector_type(4)));

__device__ __forceinline__ unsigned f2bf_u(float f) {
  unsigned u = __float_as_uint(f);
  return (u + 0x7FFFu + ((u >> 16) & 1u)) >> 16;   // round-to-nearest-even
}
__device__ __forceinline__ uint2 pack4(float4 v) {
  uint2 r;
  r.x = f2bf_u(v.x) | (f2bf_u(v.y) << 16);
  r.y = f2bf_u(v.z) | (f2bf_u(v.w) << 16);
  return r;
}

// [R][4096] f32 -> [R][KAUG] bf16 (cols 0..4095). Used for x and weight.
__global__ void k_cvt_pad(const float* __restrict__ src, unsigned short* __restrict__ dst) {
  int i = blockIdx.x * blockDim.x + threadIdx.x;
  int idx = i << 2;
  int row = idx / IN_DIM;
  int col = idx - row * IN_DIM;
  float4 v = *reinterpret_cast<const float4*>(src + idx);
  *reinterpret_cast<uint2*>(dst + row * KAUG + col) = pack4(v);
}

// A_buffer [8][64][4096] f32 -> flat [512][4096] bf16
__global__ void k_cvt_flat(const float* __restrict__ src, unsigned short* __restrict__ dst) {
  int i = blockIdx.x * blockDim.x + threadIdx.x;
  int idx = i << 2;
  float4 v = *reinterpret_cast<const float4*>(src + idx);
  *reinterpret_cast<uint2*>(dst + idx) = pack4(v);
}

// B_buffer [8][4096][64] f32 -> Waug[o][4096 + a*64 + r] bf16
__global__ void k_cvt_b(const float* __restrict__ src, unsigned short* __restrict__ dst) {
  int i = blockIdx.x * blockDim.x + threadIdx.x;
  int idx = i << 2;
  int a = idx / (OUT_DIM * RANK);
  int rem = idx - a * (OUT_DIM * RANK);
  int o = rem / RANK;
  int r = rem - o * RANK;
  float4 v = *reinterpret_cast<const float4*>(src + idx);
  *reinterpret_cast<uint2*>(dst + o * KAUG + IN_DIM + a * RANK + r) = pack4(v);
}

// C = A[M,K](row-major, lda) x B[N,K](row-major, ldb)^T
// EPI==0: out[t*N+o] = acc + bias[o]   (f32)
// EPI==1: Z[t*KAUG + IN_DIM + n] = (n>>6 == aid[t]) ? bf16(acc) : 0
template <int EPI>
__global__ __launch_bounds__(256)
void gemm_bt(const unsigned short* __restrict__ A, int lda,
             const unsigned short* __restrict__ B, int ldb,
             int M, int N, int K,
             float* __restrict__ out, const float* __restrict__ bias,
             unsigned short* __restrict__ Z, const int* __restrict__ aid) {
  constexpr int BM = 128, BN = 128, BK = 32;
  __shared__ __align__(16) unsigned short As[BM * BK];
  __shared__ __align__(16) unsigned short Bs[BN * BK];

  const int tid = threadIdx.x;
  const int w = tid >> 6;
  const int l = tid & 63;
  const int wr = w >> 1, wc = w & 1;

  // XCD-aware bijective swizzle (nwg % 8 == 0 for all our launches)
  const int nbx = N / BN;
  const int nwg = nbx * (M / BM);
  const int cpx = nwg >> 3;
  const int bid = blockIdx.x;
  const int swz = (bid & 7) * cpx + (bid >> 3);
  const int by = swz / nbx, bx = swz - by * nbx;
  const int brow = by * BM, bcol = bx * BN;

  // staging: each thread moves 16B; inst covers 64 tile rows
  const unsigned short* ga = A + (brow + (tid >> 2)) * lda + ((tid & 3) << 3);
  const unsigned short* gb = B + (bcol + (tid >> 2)) * ldb + ((tid & 3) << 3);
  unsigned short* sa = As + w * 512;   // wave-uniform LDS base (HW adds lane*16B)
  unsigned short* sb = Bs + w * 512;
  const int ga2 = 64 * lda;
  const int gb2 = 64 * ldb;

  // MFMA fragment read addresses (16x16x32 bf16: A row = l&15, k = (l>>4)*8+i)
  const int lr = l & 15;
  const int lkb = (l >> 4) << 3;
  const unsigned short* fa = As + (wr * 64 + lr) * BK + lkb;
  const unsigned short* fb = Bs + (wc * 64 + lr) * BK + lkb;

  f32x4 acc[4][4] = {};

  for (int k0 = 0; k0 < K; k0 += BK) {
    __builtin_amdgcn_global_load_lds(
        (const __attribute__((address_space(1))) void*)(ga + k0),
        (__attribute__((address_space(3))) void*)(sa), 16, 0, 0);
    __builtin_amdgcn_global_load_lds(
        (const __attribute__((address_space(1))) void*)(ga + k0 + ga2),
        (__attribute__((address_space(3))) void*)(sa + 2048), 16, 0, 0);
    __builtin_amdgcn_global_load_lds(
        (const __attribute__((address_space(1))) void*)(gb + k0),
        (__attribute__((address_space(3))) void*)(sb), 16, 0, 0);
    __builtin_amdgcn_global_load_lds(
        (const __attribute__((address_space(1))) void*)(gb + k0 + gb2),
        (__attribute__((address_space(3))) void*)(sb + 2048), 16, 0, 0);
    __syncthreads();  // drains vmcnt(0): tiles visible

    bf16x8 av[4], bv[4];
#pragma unroll
    for (int m = 0; m < 4; ++m)
      av[m] = *reinterpret_cast<const bf16x8*>(fa + m * 16 * BK);
#pragma unroll
    for (int n = 0; n < 4; ++n)
      bv[n] = *reinterpret_cast<const bf16x8*>(fb + n * 16 * BK);
#pragma unroll
    for (int m = 0; m < 4; ++m)
#pragma unroll
      for (int n = 0; n < 4; ++n)
        acc[m][n] = __builtin_amdgcn_mfma_f32_16x16x32_bf16(av[m], bv[n], acc[m][n], 0, 0, 0);
    __syncthreads();  // reads done before next stage overwrites
  }

  // D layout: row = (l>>4)*4 + j, col = l&15 (within 16x16 fragment)
  const int orow = brow + wr * 64 + ((l >> 4) << 2);
  const int ocol = bcol + wc * 64 + lr;
  if constexpr (EPI == 0) {
#pragma unroll
    for (int m = 0; m < 4; ++m)
#pragma unroll
      for (int n = 0; n < 4; ++n) {
        float bb = bias[ocol + n * 16];
#pragma unroll
        for (int j = 0; j < 4; ++j)
          out[(orow + m * 16 + j) * N + ocol + n * 16] = acc[m][n][j] + bb;
      }
  } else {
#pragma unroll
    for (int m = 0; m < 4; ++m) {
#pragma unroll
      for (int j = 0; j < 4; ++j) {
        int t = orow + m * 16 + j;
        int ad = aid[t];
#pragma unroll
        for (int n = 0; n < 4; ++n) {
          int cc = ocol + n * 16;
          float v = ((cc >> 6) == ad) ? acc[m][n][j] : 0.f;
          Z[t * KAUG + IN_DIM + cc] = (unsigned short)f2bf_u(v);
        }
      }
    }
  }
}

extern "C" void kernel_launch(void* const* d_in, const int* in_sizes, int n_in,
                              void* d_out, int out_size, void* d_ws, size_t ws_size,
                              hipStream_t stream) {
  const float* x    = (const float*)d_in[0];
  const float* wgt  = (const float*)d_in[1];
  const float* bias = (const float*)d_in[2];
  const float* Abuf = (const float*)d_in[3];
  const float* Bbuf = (const float*)d_in[4];
  const int*   aid  = (const int*)d_in[5];
  float* out = (float*)d_out;

  // workspace layout (bf16 as ushort): Xaug[8192][4608] | Waug[4096][4608] | Abf[512][4096]
  unsigned short* Xaug = (unsigned short*)d_ws;                       // 75,497,472 B
  unsigned short* Waug = Xaug + (size_t)NUM_TOKENS * KAUG;            // 37,748,736 B
  unsigned short* Abf  = Waug + (size_t)OUT_DIM * KAUG;               //  4,194,304 B

  k_cvt_pad<<<NUM_TOKENS * (IN_DIM / 4) / 256, 256, 0, stream>>>(x, Xaug);
  k_cvt_pad<<<OUT_DIM * (IN_DIM / 4) / 256, 256, 0, stream>>>(wgt, Waug);
  k_cvt_b<<<NUM_AD * OUT_DIM * (RANK / 4) / 256, 256, 0, stream>>>(Bbuf, Waug);
  k_cvt_flat<<<RTOT * (IN_DIM / 4) / 256, 256, 0, stream>>>(Abuf, Abf);

  // Z = mask(X @ A_flat^T): writes Xaug cols 4096..4607 (bf16), M=8192 N=512 K=4096
  gemm_bt<1><<<(NUM_TOKENS / 128) * (RTOT / 128), 256, 0, stream>>>(
      Xaug, KAUG, Abf, IN_DIM, NUM_TOKENS, RTOT, IN_DIM,
      nullptr, nullptr, Xaug, aid);

  // out = Xaug @ Waug^T + bias: M=8192 N=4096 K=4608
  gemm_bt<0><<<(NUM_TOKENS / 128) * (OUT_DIM / 128), 256, 0, stream>>>(
      Xaug, KAUG, Waug, KAUG, NUM_TOKENS, OUT_DIM, KAUG,
      out, bias, nullptr, nullptr);
}

// Round 2
// 403.195 us; speedup vs baseline: 1.4479x; 1.4479x over previous
//
#include <hip/hip_runtime.h>
#include <hip/hip_bf16.h>
#include <cstdint>

#define NUM_TOKENS 8192
#define IN_DIM 4096
#define OUT_DIM 4096
#define NUM_AD 8
#define RANK 64
#define RTOT (NUM_AD * RANK)           // 512
#define KAUG (IN_DIM + RTOT)           // 4608

typedef __bf16 bf16x8 __attribute__((ext_vector_type(8)));
typedef float f32x4 __attribute__((ext_vector_type(4)));
typedef unsigned short ushort_t;

__device__ __forceinline__ unsigned f2bf_u(float f) {
  unsigned u = __float_as_uint(f);
  return (u + 0x7FFFu + ((u >> 16) & 1u)) >> 16;   // round-to-nearest-even
}
__device__ __forceinline__ uint2 pack4(float4 v) {
  uint2 r;
  r.x = f2bf_u(v.x) | (f2bf_u(v.y) << 16);
  r.y = f2bf_u(v.z) | (f2bf_u(v.w) << 16);
  return r;
}

// [R][4096] f32 -> [R][KAUG] bf16 (cols 0..4095). Used for x and weight.
__global__ void k_cvt_pad(const float* __restrict__ src, ushort_t* __restrict__ dst) {
  int i = blockIdx.x * blockDim.x + threadIdx.x;
  int idx = i << 2;
  int row = idx / IN_DIM;
  int col = idx - row * IN_DIM;
  float4 v = *reinterpret_cast<const float4*>(src + idx);
  *reinterpret_cast<uint2*>(dst + row * KAUG + col) = pack4(v);
}

// A_buffer [8][64][4096] f32 -> flat [512][4096] bf16
__global__ void k_cvt_flat(const float* __restrict__ src, ushort_t* __restrict__ dst) {
  int i = blockIdx.x * blockDim.x + threadIdx.x;
  int idx = i << 2;
  float4 v = *reinterpret_cast<const float4*>(src + idx);
  *reinterpret_cast<uint2*>(dst + idx) = pack4(v);
}

// B_buffer [8][4096][64] f32 -> Waug[o][4096 + a*64 + r] bf16
__global__ void k_cvt_b(const float* __restrict__ src, ushort_t* __restrict__ dst) {
  int i = blockIdx.x * blockDim.x + threadIdx.x;
  int idx = i << 2;
  int a = idx / (OUT_DIM * RANK);
  int rem = idx - a * (OUT_DIM * RANK);
  int o = rem / RANK;
  int r = rem - o * RANK;
  float4 v = *reinterpret_cast<const float4*>(src + idx);
  *reinterpret_cast<uint2*>(dst + o * KAUG + IN_DIM + a * RANK + r) = pack4(v);
}

// ---------- 128^2-tile 2-phase GEMM, kept for the small (N=512) LoRA-A GEMM ----------
// Z[t*KAUG + IN_DIM + n] = (n>>6 == aid[t]) ? bf16(acc) : 0
__global__ __launch_bounds__(256)
void gemm_lora_a(const ushort_t* __restrict__ A, int lda,
                 const ushort_t* __restrict__ B, int ldb,
                 int M, int N, int K,
                 ushort_t* __restrict__ Z, const int* __restrict__ aid) {
  constexpr int BK = 32;
  __shared__ __align__(16) ushort_t As[128 * BK];
  __shared__ __align__(16) ushort_t Bs[128 * BK];

  const int tid = threadIdx.x;
  const int w = tid >> 6;
  const int l = tid & 63;
  const int wr = w >> 1, wc = w & 1;

  const int nbx = N / 128;
  const int nwg = nbx * (M / 128);
  const int cpx = nwg >> 3;
  const int bid = blockIdx.x;
  const int swz = (bid & 7) * cpx + (bid >> 3);
  const int by = swz / nbx, bx = swz - by * nbx;
  const int brow = by * 128, bcol = bx * 128;

  const ushort_t* ga = A + (brow + (tid >> 2)) * lda + ((tid & 3) << 3);
  const ushort_t* gb = B + (bcol + (tid >> 2)) * ldb + ((tid & 3) << 3);
  ushort_t* sa = As + w * 512;
  ushort_t* sb = Bs + w * 512;
  const int ga2 = 64 * lda;
  const int gb2 = 64 * ldb;

  const int lr = l & 15;
  const int lkb = (l >> 4) << 3;
  const ushort_t* fa = As + (wr * 64 + lr) * BK + lkb;
  const ushort_t* fb = Bs + (wc * 64 + lr) * BK + lkb;

  f32x4 acc[4][4] = {};

  for (int k0 = 0; k0 < K; k0 += BK) {
    __builtin_amdgcn_global_load_lds(
        (const __attribute__((address_space(1))) void*)(ga + k0),
        (__attribute__((address_space(3))) void*)(sa), 16, 0, 0);
    __builtin_amdgcn_global_load_lds(
        (const __attribute__((address_space(1))) void*)(ga + k0 + ga2),
        (__attribute__((address_space(3))) void*)(sa + 2048), 16, 0, 0);
    __builtin_amdgcn_global_load_lds(
        (const __attribute__((address_space(1))) void*)(gb + k0),
        (__attribute__((address_space(3))) void*)(sb), 16, 0, 0);
    __builtin_amdgcn_global_load_lds(
        (const __attribute__((address_space(1))) void*)(gb + k0 + gb2),
        (__attribute__((address_space(3))) void*)(sb + 2048), 16, 0, 0);
    __syncthreads();

    bf16x8 av[4], bv[4];
#pragma unroll
    for (int m = 0; m < 4; ++m)
      av[m] = *reinterpret_cast<const bf16x8*>(fa + m * 16 * BK);
#pragma unroll
    for (int n = 0; n < 4; ++n)
      bv[n] = *reinterpret_cast<const bf16x8*>(fb + n * 16 * BK);
#pragma unroll
    for (int m = 0; m < 4; ++m)
#pragma unroll
      for (int n = 0; n < 4; ++n)
        acc[m][n] = __builtin_amdgcn_mfma_f32_16x16x32_bf16(av[m], bv[n], acc[m][n], 0, 0, 0);
    __syncthreads();
  }

  const int orow = brow + wr * 64 + ((l >> 4) << 2);
  const int ocol = bcol + wc * 64 + lr;
#pragma unroll
  for (int m = 0; m < 4; ++m) {
#pragma unroll
    for (int j = 0; j < 4; ++j) {
      int t = orow + m * 16 + j;
      int ad = aid[t];
#pragma unroll
      for (int n = 0; n < 4; ++n) {
        int cc = ocol + n * 16;
        float v = ((cc >> 6) == ad) ? acc[m][n][j] : 0.f;
        Z[t * KAUG + IN_DIM + cc] = (ushort_t)f2bf_u(v);
      }
    }
  }
}

// ---------- 256^2-tile 8-phase counted-vmcnt GEMM (m201 template, plain HIP) ----------
// C[M,N] = A[M,K](lda) x B[N,K](ldb)^T + bias.  M,N % 256 == 0, K % 128 == 0.
// 8 waves (2Mx4N), per-wave C = 128x64. LDS 128KB: 2 bufs x (A:2x16KB | B:2x16KB).
// Half-tile = 128 rows x 64 cols bf16, staged by 2 global_load_lds (512thr x 16B).
// T2 read-swizzle: byte ^= ((row&7)<<4); source pre-swizzled with same involution.
__global__ __launch_bounds__(512, 2)
void gemm8(const ushort_t* __restrict__ A, int lda,
           const ushort_t* __restrict__ B, int ldb,
           int M, int N, int K,
           float* __restrict__ out, const float* __restrict__ bias) {
  extern __shared__ char lds[];
  const int tid = threadIdx.x;
  const int l = tid & 63;
  const int w = tid >> 6;       // 0..7
  const int wr = w >> 2;        // 0..1  (A-half / M-half ownership)
  const int wc = w & 3;         // 0..3  (N ownership: B-half wc>>1, 64-col slice wc&1)

  const int nbx = N >> 8;
  const int nwg = nbx * (M >> 8);
  const int cpx = nwg >> 3;     // nwg % 8 == 0 for all our launches
  const int bid = blockIdx.x;
  const int swz = (bid & 7) * cpx + (bid >> 3);
  const int by = swz / nbx, bx = swz - by * nbx;
  const int brow = by << 8, bcol = bx << 8;

  // stage-side constants (thread t writes LDS linear bytes j*8192 + t*16,
  // i.e. row j*64 + (t>>3), byte-in-row (t&7)*16; source col pre-swizzled)
  const int r0 = tid >> 3;                        // 0..63
  const int kc = ((tid & 7) ^ (r0 & 7)) << 3;     // element col, same involution as read

  // read-side constants
  const int lr = l & 15;
  const int lxor = (l & 7) << 4;                  // (row&7)<<4
  const int kb0 = (l >> 4) << 4;                  // 0,16,32,48 bytes

  const int NT = K >> 6;         // K-tiles (even)
  const int NIT = NT >> 1;

#define AS1(p) (const __attribute__((address_space(1))) void*)(p)
#define AS3(p) (__attribute__((address_space(3))) void*)(p)

  // stage one half-tile (2 x global_load_lds). buf = kt&1.
#define STG(mat, ld, rowbase, kt_, half, isB) do {                                   \
    int kt = (kt_); if (kt >= NT) kt -= NT;                                          \
    char* lb = lds + (((kt & 1) << 16) | ((isB) << 15) | ((half) << 14) | (w << 10));\
    const ushort_t* sp = (mat) + (size_t)((rowbase) + ((half) << 7) + r0) * (ld)     \
                         + (kt << 6) + kc;                                           \
    __builtin_amdgcn_global_load_lds(AS1(sp), AS3(lb), 16, 0, 0);                    \
    __builtin_amdgcn_global_load_lds(AS1(sp + 64 * (ld)), AS3(lb + 8192), 16, 0, 0); \
  } while (0)

#define LDA_ADDR(c, q, m, ks)                                                        \
  (const bf16x8*)(lds + (((c) << 16) | (wr << 14))                                   \
                  + ((q) * 32 + (m) * 16 + lr) * 128 + ((((ks) << 6) | kb0) ^ lxor))
#define LDB_ADDR(c, n, ks)                                                           \
  (const bf16x8*)(lds + (((c) << 16) | 32768 | ((wc >> 1) << 14))                    \
                  + (((wc & 1) << 6) + (n) * 16 + lr) * 128 + ((((ks) << 6) | kb0) ^ lxor))

  f32x4 acc[8][4] = {};
  bf16x8 bfr[4][2];   // B-frags for current K-tile, loaded at q==0, reused q=1..3

  // prologue: T0 complete + T1.B0/B1 in flight => enter steady state
  STG(A, lda, brow, 0, 0, 0);
  STG(A, lda, brow, 0, 1, 0);
  STG(B, ldb, bcol, 0, 0, 1);
  STG(B, ldb, bcol, 0, 1, 1);
  STG(B, ldb, bcol, 1, 0, 1);
  STG(B, ldb, bcol, 1, 1, 1);
  asm volatile("s_waitcnt vmcnt(4)" ::: "memory");   // T0's 8 loads landed
  __builtin_amdgcn_s_barrier();

  // phase: ds_read subtile || stage 1 half-tile -> [vmcnt] -> barrier -> lgkmcnt(0)
  //        -> setprio(1) 16xMFMA setprio(0) -> barrier
#define PHASE(c, q, LOADB, VM, ...)                                                  \
  do {                                                                               \
    bf16x8 afr[2][2];                                                                \
    _Pragma("unroll") for (int m = 0; m < 2; ++m)                                    \
      _Pragma("unroll") for (int ks = 0; ks < 2; ++ks)                               \
        afr[m][ks] = *LDA_ADDR(c, q, m, ks);                                         \
    if (LOADB) {                                                                     \
      _Pragma("unroll") for (int n = 0; n < 4; ++n)                                  \
        _Pragma("unroll") for (int ks = 0; ks < 2; ++ks)                             \
          bfr[n][ks] = *LDB_ADDR(c, n, ks);                                          \
    }                                                                                \
    __VA_ARGS__;                                                                     \
    if (VM) { asm volatile("s_waitcnt vmcnt(4)" ::: "memory"); }                     \
    __builtin_amdgcn_s_barrier();                                                    \
    asm volatile("s_waitcnt lgkmcnt(0)" ::: "memory");                               \
    __builtin_amdgcn_sched_barrier(0);                                               \
    __builtin_amdgcn_s_setprio(1);                                                   \
    _Pragma("unroll") for (int ks = 0; ks < 2; ++ks)                                 \
      _Pragma("unroll") for (int m = 0; m < 2; ++m)                                  \
        _Pragma("unroll") for (int n = 0; n < 4; ++n)                                \
          acc[2 * (q) + m][n] = __builtin_amdgcn_mfma_f32_16x16x32_bf16(             \
              afr[m][ks], bfr[n][ks], acc[2 * (q) + m][n], 0, 0, 0);                 \
    __builtin_amdgcn_s_setprio(0);                                                   \
    __builtin_amdgcn_s_barrier();                                                    \
  } while (0)

  for (int it = 0; it < NIT; ++it) {
    const int T = it << 1;
    PHASE(0, 0, 1, 0, STG(A, lda, brow, T + 1, 0, 0));
    PHASE(0, 1, 0, 0, STG(A, lda, brow, T + 1, 1, 0));
    PHASE(0, 2, 0, 0, STG(B, ldb, bcol, T + 2, 0, 1));
    PHASE(0, 3, 0, 1, STG(B, ldb, bcol, T + 2, 1, 1));   // vmcnt(4): T+1 complete
    PHASE(1, 0, 1, 0, STG(A, lda, brow, T + 2, 0, 0));
    PHASE(1, 1, 0, 0, STG(A, lda, brow, T + 2, 1, 0));
    PHASE(1, 2, 0, 0, STG(B, ldb, bcol, T + 3, 0, 1));
    PHASE(1, 3, 0, 1, STG(B, ldb, bcol, T + 3, 1, 1));   // vmcnt(4): T+2 complete
  }

  // epilogue: D frag layout row=(l>>4)*4+j, col=l&15 (same convention as R1, verified)
  const int orow = brow + (wr << 7) + ((l >> 4) << 2);
  const int ocol = bcol + (wc << 6) + lr;
  float bb[4];
#pragma unroll
  for (int n = 0; n < 4; ++n) bb[n] = bias[ocol + n * 16];
#pragma unroll
  for (int mi = 0; mi < 8; ++mi)
#pragma unroll
    for (int n = 0; n < 4; ++n)
#pragma unroll
      for (int j = 0; j < 4; ++j)
        out[(size_t)(orow + mi * 16 + j) * N + ocol + n * 16] = acc[mi][n][j] + bb[n];
}

extern "C" void kernel_launch(void* const* d_in, const int* in_sizes, int n_in,
                              void* d_out, int out_size, void* d_ws, size_t ws_size,
                              hipStream_t stream) {
  const float* x    = (const float*)d_in[0];
  const float* wgt  = (const float*)d_in[1];
  const float* bias = (const float*)d_in[2];
  const float* Abuf = (const float*)d_in[3];
  const float* Bbuf = (const float*)d_in[4];
  const int*   aid  = (const int*)d_in[5];
  float* out = (float*)d_out;

  // workspace: Xaug[8192][4608] | Waug[4096][4608] | Abf[512][4096]  (bf16 as ushort)
  ushort_t* Xaug = (ushort_t*)d_ws;
  ushort_t* Waug = Xaug + (size_t)NUM_TOKENS * KAUG;
  ushort_t* Abf  = Waug + (size_t)OUT_DIM * KAUG;

  k_cvt_pad<<<NUM_TOKENS * (IN_DIM / 4) / 256, 256, 0, stream>>>(x, Xaug);
  k_cvt_pad<<<OUT_DIM * (IN_DIM / 4) / 256, 256, 0, stream>>>(wgt, Waug);
  k_cvt_b<<<NUM_AD * OUT_DIM * (RANK / 4) / 256, 256, 0, stream>>>(Bbuf, Waug);
  k_cvt_flat<<<RTOT * (IN_DIM / 4) / 256, 256, 0, stream>>>(Abuf, Abf);

  // Z = mask(X @ A_flat^T) into Xaug cols 4096..4607: M=8192 N=512 K=4096
  gemm_lora_a<<<(NUM_TOKENS / 128) * (RTOT / 128), 256, 0, stream>>>(
      Xaug, KAUG, Abf, IN_DIM, NUM_TOKENS, RTOT, IN_DIM, Xaug, aid);

  // out = Xaug @ Waug^T + bias: M=8192 N=4096 K=4608 (72 K-tiles, 36 iters)
  gemm8<<<(NUM_TOKENS / 256) * (OUT_DIM / 256), 512, 131072, stream>>>(
      Xaug, KAUG, Waug, KAUG, NUM_TOKENS, OUT_DIM, KAUG, out, bias);
}

// Round 3
// 384.589 us; speedup vs baseline: 1.5180x; 1.0484x over previous
//
#include <hip/hip_runtime.h>
#include <hip/hip_bf16.h>
#include <cstdint>

#define NUM_TOKENS 8192
#define IN_DIM 4096
#define OUT_DIM 4096
#define NUM_AD 8
#define RANK 64
#define RTOT (NUM_AD * RANK)           // 512
#define KAUG (IN_DIM + RTOT)           // 4608

typedef __bf16 bf16x8 __attribute__((ext_vector_type(8)));
typedef float f32x4 __attribute__((ext_vector_type(4)));
typedef unsigned short ushort_t;

__device__ __forceinline__ unsigned f2bf_u(float f) {
  unsigned u = __float_as_uint(f);
  return (u + 0x7FFFu + ((u >> 16) & 1u)) >> 16;   // round-to-nearest-even
}
__device__ __forceinline__ uint2 pack4(float4 v) {
  uint2 r;
  r.x = f2bf_u(v.x) | (f2bf_u(v.y) << 16);
  r.y = f2bf_u(v.z) | (f2bf_u(v.w) << 16);
  return r;
}

// [R][4096] f32 -> [R][KAUG] bf16 (cols 0..4095). Used for x and weight.
__global__ void k_cvt_pad(const float* __restrict__ src, ushort_t* __restrict__ dst) {
  int i = blockIdx.x * blockDim.x + threadIdx.x;
  int idx = i << 2;
  int row = idx / IN_DIM;
  int col = idx - row * IN_DIM;
  float4 v = *reinterpret_cast<const float4*>(src + idx);
  *reinterpret_cast<uint2*>(dst + row * KAUG + col) = pack4(v);
}

// A_buffer [8][64][4096] f32 -> flat [512][4096] bf16
__global__ void k_cvt_flat(const float* __restrict__ src, ushort_t* __restrict__ dst) {
  int i = blockIdx.x * blockDim.x + threadIdx.x;
  int idx = i << 2;
  float4 v = *reinterpret_cast<const float4*>(src + idx);
  *reinterpret_cast<uint2*>(dst + idx) = pack4(v);
}

// B_buffer [8][4096][64] f32 -> Waug[o][4096 + a*64 + r] bf16
__global__ void k_cvt_b(const float* __restrict__ src, ushort_t* __restrict__ dst) {
  int i = blockIdx.x * blockDim.x + threadIdx.x;
  int idx = i << 2;
  int a = idx / (OUT_DIM * RANK);
  int rem = idx - a * (OUT_DIM * RANK);
  int o = rem / RANK;
  int r = rem - o * RANK;
  float4 v = *reinterpret_cast<const float4*>(src + idx);
  *reinterpret_cast<uint2*>(dst + o * KAUG + IN_DIM + a * RANK + r) = pack4(v);
}

// ---------- 128^2-tile 2-phase GEMM, kept for the small (N=512) LoRA-A GEMM ----------
// Z[t*KAUG + IN_DIM + n] = (n>>6 == aid[t]) ? bf16(acc) : 0
__global__ __launch_bounds__(256)
void gemm_lora_a(const ushort_t* __restrict__ A, int lda,
                 const ushort_t* __restrict__ B, int ldb,
                 int M, int N, int K,
                 ushort_t* __restrict__ Z, const int* __restrict__ aid) {
  constexpr int BK = 32;
  __shared__ __align__(16) ushort_t As[128 * BK];
  __shared__ __align__(16) ushort_t Bs[128 * BK];

  const int tid = threadIdx.x;
  const int w = tid >> 6;
  const int l = tid & 63;
  const int wr = w >> 1, wc = w & 1;

  const int nbx = N / 128;
  const int nwg = nbx * (M / 128);
  const int cpx = nwg >> 3;
  const int bid = blockIdx.x;
  const int swz = (bid & 7) * cpx + (bid >> 3);
  const int by = swz / nbx, bx = swz - by * nbx;
  const int brow = by * 128, bcol = bx * 128;

  const ushort_t* ga = A + (brow + (tid >> 2)) * lda + ((tid & 3) << 3);
  const ushort_t* gb = B + (bcol + (tid >> 2)) * ldb + ((tid & 3) << 3);
  ushort_t* sa = As + w * 512;
  ushort_t* sb = Bs + w * 512;
  const int ga2 = 64 * lda;
  const int gb2 = 64 * ldb;

  const int lr = l & 15;
  const int lkb = (l >> 4) << 3;
  const ushort_t* fa = As + (wr * 64 + lr) * BK + lkb;
  const ushort_t* fb = Bs + (wc * 64 + lr) * BK + lkb;

  f32x4 acc[4][4] = {};

  for (int k0 = 0; k0 < K; k0 += BK) {
    __builtin_amdgcn_global_load_lds(
        (const __attribute__((address_space(1))) void*)(ga + k0),
        (__attribute__((address_space(3))) void*)(sa), 16, 0, 0);
    __builtin_amdgcn_global_load_lds(
        (const __attribute__((address_space(1))) void*)(ga + k0 + ga2),
        (__attribute__((address_space(3))) void*)(sa + 2048), 16, 0, 0);
    __builtin_amdgcn_global_load_lds(
        (const __attribute__((address_space(1))) void*)(gb + k0),
        (__attribute__((address_space(3))) void*)(sb), 16, 0, 0);
    __builtin_amdgcn_global_load_lds(
        (const __attribute__((address_space(1))) void*)(gb + k0 + gb2),
        (__attribute__((address_space(3))) void*)(sb + 2048), 16, 0, 0);
    __syncthreads();

    bf16x8 av[4], bv[4];
#pragma unroll
    for (int m = 0; m < 4; ++m)
      av[m] = *reinterpret_cast<const bf16x8*>(fa + m * 16 * BK);
#pragma unroll
    for (int n = 0; n < 4; ++n)
      bv[n] = *reinterpret_cast<const bf16x8*>(fb + n * 16 * BK);
#pragma unroll
    for (int m = 0; m < 4; ++m)
#pragma unroll
      for (int n = 0; n < 4; ++n)
        acc[m][n] = __builtin_amdgcn_mfma_f32_16x16x32_bf16(av[m], bv[n], acc[m][n], 0, 0, 0);
    __syncthreads();
  }

  const int orow = brow + wr * 64 + ((l >> 4) << 2);
  const int ocol = bcol + wc * 64 + lr;
#pragma unroll
  for (int m = 0; m < 4; ++m) {
#pragma unroll
    for (int j = 0; j < 4; ++j) {
      int t = orow + m * 16 + j;
      int ad = aid[t];
#pragma unroll
      for (int n = 0; n < 4; ++n) {
        int cc = ocol + n * 16;
        float v = ((cc >> 6) == ad) ? acc[m][n][j] : 0.f;
        Z[t * KAUG + IN_DIM + cc] = (ushort_t)f2bf_u(v);
      }
    }
  }
}

// ---------- 256^2-tile sparse-barrier counted-vmcnt GEMM ----------
// C[M,N] = A[M,K](lda) x B[N,K](ldb)^T + bias.  M,N % 256 == 0, K % 128 == 0.
// 8 waves (2Mx4N), per-wave C = 128x64. LDS 128KB: 2 bufs x (A:2x16KB | B:2x16KB).
// 2 barriers + 2 vmcnt(4) per K-tile. B-frags register-pipelined: loaded for
// tile T+1 at the END of tile T's second region (WAR on bfr pins order).
// T2 read-swizzle: byte ^= ((row&7)<<4); source pre-swizzled (same involution).
__global__ __launch_bounds__(512, 2)
void gemm8(const ushort_t* __restrict__ A, int lda,
           const ushort_t* __restrict__ B, int ldb,
           int M, int N, int K,
           float* __restrict__ out, const float* __restrict__ bias) {
  extern __shared__ char lds[];
  const int tid = threadIdx.x;
  const int l = tid & 63;
  const int w = tid >> 6;       // 0..7
  const int wr = w >> 2;        // 0..1  (A-half / M-half ownership)
  const int wc = w & 3;         // 0..3  (N ownership: B-half wc>>1, 64-col slice wc&1)

  const int nbx = N >> 8;
  const int nwg = nbx * (M >> 8);
  const int cpx = nwg >> 3;     // nwg % 8 == 0 for all our launches
  const int bid = blockIdx.x;
  const int swz = (bid & 7) * cpx + (bid >> 3);
  const int by = swz / nbx, bx = swz - by * nbx;
  const int brow = by << 8, bcol = bx << 8;

  // stage-side constants (thread t writes LDS linear bytes j*8192 + t*16,
  // i.e. row j*64 + (t>>3), byte-in-row (t&7)*16; source col pre-swizzled)
  const int r0 = tid >> 3;                        // 0..63
  const int kc = ((tid & 7) ^ (r0 & 7)) << 3;     // element col, same involution as read

  // read-side constants
  const int lr = l & 15;
  const int lxor = (l & 7) << 4;                  // (row&7)<<4
  const int kb0 = (l >> 4) << 4;                  // 0,16,32,48 bytes

  const int NT = K >> 6;         // K-tiles (even)
  const int NIT = NT >> 1;

#define AS1(p) (const __attribute__((address_space(1))) void*)(p)
#define AS3(p) (__attribute__((address_space(3))) void*)(p)

  // stage one half-tile (2 x global_load_lds). buf = kt&1.
#define STG(mat, ld, rowbase, kt_, half, isB) do {                                   \
    int kt = (kt_); if (kt >= NT) kt -= NT;                                          \
    char* lb = lds + (((kt & 1) << 16) | ((isB) << 15) | ((half) << 14) | (w << 10));\
    const ushort_t* sp = (mat) + (size_t)((rowbase) + ((half) << 7) + r0) * (ld)     \
                         + (kt << 6) + kc;                                           \
    __builtin_amdgcn_global_load_lds(AS1(sp), AS3(lb), 16, 0, 0);                    \
    __builtin_amdgcn_global_load_lds(AS1(sp + 64 * (ld)), AS3(lb + 8192), 16, 0, 0); \
  } while (0)

#define LDA_ADDR(c, q, m, ks)                                                        \
  (const bf16x8*)(lds + (((c) << 16) | (wr << 14))                                   \
                  + ((q) * 32 + (m) * 16 + lr) * 128 + ((((ks) << 6) | kb0) ^ lxor))
#define LDB_ADDR(c, n, ks)                                                           \
  (const bf16x8*)(lds + (((c) << 16) | 32768 | ((wc >> 1) << 14))                    \
                  + (((wc & 1) << 6) + (n) * 16 + lr) * 128 + ((((ks) << 6) | kb0) ^ lxor))

  f32x4 acc[8][4] = {};
  bf16x8 bfr[4][2];   // B-frags for the CURRENT tile; reloaded (next tile) at
                      // the end of each tile's second region (WAR-ordered).

#define LDBH(c, h, dst) do {                                                         \
    _Pragma("unroll") for (int n = 2 * (h); n < 2 * (h) + 2; ++n)                    \
      _Pragma("unroll") for (int ks = 0; ks < 2; ++ks)                               \
        dst[n][ks] = *LDB_ADDR(c, n, ks);                                            \
  } while (0)

#define MFMAQ(q, a_, bfr_)                                                           \
    _Pragma("unroll") for (int ks = 0; ks < 2; ++ks)                                 \
      _Pragma("unroll") for (int m = 0; m < 2; ++m)                                  \
        _Pragma("unroll") for (int n = 0; n < 4; ++n)                                \
          acc[2 * (q) + m][n] = __builtin_amdgcn_mfma_f32_16x16x32_bf16(             \
              a_[m][ks], bfr_[n][ks], acc[2 * (q) + m][n], 0, 0, 0)

  // prologue: T0 A+B complete, T1.B in flight; B(0)->bfr in registers
  STG(A, lda, brow, 0, 0, 0);
  STG(A, lda, brow, 0, 1, 0);
  STG(B, ldb, bcol, 0, 0, 1);
  STG(B, ldb, bcol, 0, 1, 1);
  STG(B, ldb, bcol, 1, 0, 1);
  STG(B, ldb, bcol, 1, 1, 1);
  asm volatile("s_waitcnt vmcnt(4)" ::: "memory");
  __builtin_amdgcn_s_barrier();
  __builtin_amdgcn_sched_barrier(0);
  LDBH(0, 0, bfr);
  LDBH(0, 1, bfr);

  // one K-tile: region01 {A-reads q0,q1 | stage A(T+1) | MFMA q0,q1 | vmcnt(4) bar}
  //             region23 {A-reads q2,q3 | stage B(T+2) | MFMA q2,q3 |
  //                       late-load bfr <- B(T+1) | vmcnt(4) bar}
#define TILE(c, TA, TB) do {                                                         \
    {                                                                                \
      bf16x8 a0[2][2], a1[2][2];                                                     \
      _Pragma("unroll") for (int m = 0; m < 2; ++m)                                  \
        _Pragma("unroll") for (int ks = 0; ks < 2; ++ks) {                           \
          a0[m][ks] = *LDA_ADDR(c, 0, m, ks);                                        \
          a1[m][ks] = *LDA_ADDR(c, 1, m, ks);                                        \
        }                                                                            \
      STG(A, lda, brow, TA, 0, 0);                                                   \
      STG(A, lda, brow, TA, 1, 0);                                                   \
      __builtin_amdgcn_s_setprio(1);                                                 \
      MFMAQ(0, a0, bfr);                                                             \
      MFMAQ(1, a1, bfr);                                                             \
      __builtin_amdgcn_s_setprio(0);                                                 \
      asm volatile("s_waitcnt vmcnt(4)" ::: "memory");                               \
      __builtin_amdgcn_s_barrier();                                                  \
      __builtin_amdgcn_sched_barrier(0);                                             \
    }                                                                                \
    {                                                                                \
      bf16x8 a0[2][2], a1[2][2];                                                     \
      _Pragma("unroll") for (int m = 0; m < 2; ++m)                                  \
        _Pragma("unroll") for (int ks = 0; ks < 2; ++ks) {                           \
          a0[m][ks] = *LDA_ADDR(c, 2, m, ks);                                        \
          a1[m][ks] = *LDA_ADDR(c, 3, m, ks);                                        \
        }                                                                            \
      STG(B, ldb, bcol, TB, 0, 1);                                                   \
      STG(B, ldb, bcol, TB, 1, 1);                                                   \
      __builtin_amdgcn_s_setprio(1);                                                 \
      MFMAQ(2, a0, bfr);                                                             \
      MFMAQ(3, a1, bfr);                                                             \
      __builtin_amdgcn_s_setprio(0);                                                 \
      LDBH((c) ^ 1, 0, bfr);                                                         \
      LDBH((c) ^ 1, 1, bfr);                                                         \
      asm volatile("s_waitcnt vmcnt(4)" ::: "memory");                               \
      __builtin_amdgcn_s_barrier();                                                  \
      __builtin_amdgcn_sched_barrier(0);                                             \
    }                                                                                \
  } while (0)

  for (int it = 0; it < NIT; ++it) {
    const int T = it << 1;
    TILE(0, T + 1, T + 2);
    TILE(1, T + 2, T + 3);
  }

  // epilogue: D frag layout row=(l>>4)*4+j, col=l&15 (verified R1/R2)
  const int orow = brow + (wr << 7) + ((l >> 4) << 2);
  const int ocol = bcol + (wc << 6) + lr;
  float bb[4];
#pragma unroll
  for (int n = 0; n < 4; ++n) bb[n] = bias[ocol + n * 16];
#pragma unroll
  for (int mi = 0; mi < 8; ++mi)
#pragma unroll
    for (int n = 0; n < 4; ++n)
#pragma unroll
      for (int j = 0; j < 4; ++j)
        out[(size_t)(orow + mi * 16 + j) * N + ocol + n * 16] = acc[mi][n][j] + bb[n];
}

extern "C" void kernel_launch(void* const* d_in, const int* in_sizes, int n_in,
                              void* d_out, int out_size, void* d_ws, size_t ws_size,
                              hipStream_t stream) {
  const float* x    = (const float*)d_in[0];
  const float* wgt  = (const float*)d_in[1];
  const float* bias = (const float*)d_in[2];
  const float* Abuf = (const float*)d_in[3];
  const float* Bbuf = (const float*)d_in[4];
  const int*   aid  = (const int*)d_in[5];
  float* out = (float*)d_out;

  // workspace: Xaug[8192][4608] | Waug[4096][4608] | Abf[512][4096]  (bf16 as ushort)
  ushort_t* Xaug = (ushort_t*)d_ws;
  ushort_t* Waug = Xaug + (size_t)NUM_TOKENS * KAUG;
  ushort_t* Abf  = Waug + (size_t)OUT_DIM * KAUG;

  k_cvt_pad<<<NUM_TOKENS * (IN_DIM / 4) / 256, 256, 0, stream>>>(x, Xaug);
  k_cvt_pad<<<OUT_DIM * (IN_DIM / 4) / 256, 256, 0, stream>>>(wgt, Waug);
  k_cvt_b<<<NUM_AD * OUT_DIM * (RANK / 4) / 256, 256, 0, stream>>>(Bbuf, Waug);
  k_cvt_flat<<<RTOT * (IN_DIM / 4) / 256, 256, 0, stream>>>(Abuf, Abf);

  // Z = mask(X @ A_flat^T) into Xaug cols 4096..4607: M=8192 N=512 K=4096
  gemm_lora_a<<<(NUM_TOKENS / 128) * (RTOT / 128), 256, 0, stream>>>(
      Xaug, KAUG, Abf, IN_DIM, NUM_TOKENS, RTOT, IN_DIM, Xaug, aid);

  // out = Xaug @ Waug^T + bias: M=8192 N=4096 K=4608 (72 K-tiles, 36 iters)
  gemm8<<<(NUM_TOKENS / 256) * (OUT_DIM / 256), 512, 131072, stream>>>(
      Xaug, KAUG, Waug, KAUG, NUM_TOKENS, OUT_DIM, KAUG, out, bias);
}